// Round 8
// baseline (409.189 us; speedup 1.0000x reference)
//
#include <hip/hip_runtime.h>
#include <hip/hip_bf16.h>
#include <math.h>

#define N_NODES 100000
#define NE      3200000
#define TWO_NE  (2 * NE)
#define TWO_N   (2 * N_NODES)
#define H       32
#define DAMPING 0.1f
#define LN_EPS  1e-5f

// Interleaved row ids: node r, sign s -> row' = 2r+s. Bucket = 256 rows = 128 nodes.
#define NBUCK    782           // ceil(2N / 256)
#define CAP_PAD  11776         // bucket region incl. 16-pads (mean padded 10112, +14 sigma)
#define CAP_STG  8960          // raw count cap (mean 8184 + 8.5 sigma)
#define RPT      ((CAP_STG + 255) / 256)   // 35 register-staged records per thread
#define EPB      8192          // edges per scatter block
#define NBLK_A   ((TWO_NE + EPB - 1) / EPB)   // 782
#define NLN      (N_NODES / 8)                // 12500 ln-role blocks
#define ZROW     TWO_N         // dedicated all-zero xh row used for padding
#define GSTRIDE  16            // gcur padding: one cursor per 64B line

// ---------------------------------------------------------------------------
// Kernel 1 (pass A): LDS counting-sort edges by coarse bucket (rank-first,
// one ds-atomic per edge), coalesced run writes of RAW records.
// Cursors are RELATIVE (memset-zeroed); absolute base = b*CAP_PAD.
// rec = (row' & 255) << 18 | src'   (interleaved ids < 2^18)
// ---------------------------------------------------------------------------
__global__ __launch_bounds__(256) void bucket_scatter_kernel(
    const int* __restrict__ ep, const int* __restrict__ en,
    int* __restrict__ gcur, unsigned int* __restrict__ buf)
{
    __shared__ int lcur[NBUCK];            // rank counters -> final counts
    __shared__ int lexcl[NBUCK];
    __shared__ int claim[NBUCK];
    __shared__ int partial[256];
    __shared__ unsigned int srec[EPB];
    __shared__ unsigned short sbid[EPB];
    __shared__ unsigned short rnk[EPB];    // per-record rank within its bucket

    int t = threadIdx.x;
    for (int i = t; i < NBUCK; i += 256) lcur[i] = 0;
    __syncthreads();

    int base = blockIdx.x * EPB;
    unsigned int regR[EPB / 256];
    short regB[EPB / 256];
    #pragma unroll
    for (int j = 0; j < EPB / 1024; j++) {
        int i = base + (j * 256 + t) * 4;   // 4-aligned; never straddles NE
        if (i < TWO_NE) {
            int g = i >= NE;                // 0 = pos edge list, 1 = neg
            int e = i - g * NE;
            const int* eix = g ? en : ep;
            int4 s4 = *(const int4*)(eix + e);
            int4 d4 = *(const int4*)(eix + NE + e);
            int ss[4] = {s4.x, s4.y, s4.z, s4.w};
            int dd[4] = {d4.x, d4.y, d4.z, d4.w};
            #pragma unroll
            for (int k = 0; k < 4; k++) {
                int src = 2 * ss[k] + g;    // interleaved ids
                int dst = 2 * dd[k] + g;
                int b = dst >> 8;
                regB[j * 4 + k] = (short)b;
                regR[j * 4 + k] = ((unsigned int)(dst & 255) << 18) | (unsigned int)src;
                int r = atomicAdd(&lcur[b], 1);             // the ONLY per-edge atomic
                rnk[((j * 4 + k) << 8) + t] = (unsigned short)r;
            }
        } else {
            #pragma unroll
            for (int k = 0; k < 4; k++) regB[j * 4 + k] = -1;
        }
    }
    __syncthreads();

    // exclusive scan over lcur[0..NBUCK): 4 cells/thread + Hillis over partials
    int h0[4]; int ssum = 0;
    #pragma unroll
    for (int k = 0; k < 4; k++) {
        int idx = t * 4 + k;
        h0[k] = (idx < NBUCK) ? lcur[idx] : 0;
        ssum += h0[k];
    }
    partial[t] = ssum;
    __syncthreads();
    for (int off = 1; off < 256; off <<= 1) {
        int u = (t >= off) ? partial[t - off] : 0;
        __syncthreads();
        partial[t] += u;
        __syncthreads();
    }
    int run = partial[t] - ssum;
    #pragma unroll
    for (int k = 0; k < 4; k++) {
        int idx = t * 4 + k;
        if (idx < NBUCK) lexcl[idx] = run;
        run += h0[k];
    }
    __syncthreads();

    // claim contiguous global space per nonempty bucket (relative cursors)
    for (int b = t; b < NBUCK; b += 256) {
        int c = lcur[b];
        claim[b] = c ? (b * CAP_PAD + atomicAdd(&gcur[b * GSTRIDE], c)) : 0;
    }
    __syncthreads();

    // atomic-free placement: sorted position = lexcl[b] + stored rank
    #pragma unroll
    for (int j = 0; j < EPB / 256; j++) {
        int b = regB[j];
        if (b >= 0) {
            int s = lexcl[b] + rnk[(j << 8) + t];
            srec[s] = regR[j];
            sbid[s] = (unsigned short)b;
        }
    }
    __syncthreads();

    // coalesced-run writes: consecutive s within a bucket -> consecutive global
    int cnt = partial[255];
    for (int s = t; s < cnt; s += 256) {
        int b = sbid[s];
        buf[claim[b] + (s - lexcl[b])] = srec[s];
    }
}

// ---------------------------------------------------------------------------
// Kernel 2 (MIXED): blocks [0,NBUCK) = csr_build (sort bucket into padded
// slots; publish inv early via device-scope atomics + release flag).
// Blocks [NBUCK, NBUCK+NLN) = ln: LN + 2 GEMVs for 8 nodes; compute first,
// acquire-spin on the (single) bucket flag only at the very end, then scale
// by atomically-loaded inv and store packed bf16 xh. In-order workgroup
// dispatch => all csr blocks scheduled before any ln block => bounded spin.
// ---------------------------------------------------------------------------
struct MixU {
    union {
        struct {                                // csr role: 50.2 KB
            unsigned int srt[CAP_PAD];
            int hist[256];
            int scn[256];
            int lcur[256];
        } c;
        struct {                                // ln role: 8 KB
            float sWp[H * H];
            float sWn[H * H];
        } l;
    };
};

__global__ __launch_bounds__(256) void mixed_csr_ln_kernel(
    const int* __restrict__ gcur,
    unsigned int* __restrict__ buf,     // bucketed in, padded slots out (in-place)
    int2* __restrict__ rs2,
    float* __restrict__ inv,
    int* __restrict__ flags,
    const float* __restrict__ h,
    const float* __restrict__ gamma,
    const float* __restrict__ beta,
    const float* __restrict__ Wp,
    const float* __restrict__ Wn,
    __hip_bfloat162* __restrict__ xh)
{
    __shared__ MixU u;
    int t = threadIdx.x;

    if (blockIdx.x < NBUCK) {
        // ------------------------------ csr role ------------------------------
        int b = blockIdx.x;
        int gbase = b * CAP_PAD;
        int cnt = gcur[b * GSTRIDE];        // relative count
        if (cnt > CAP_STG) cnt = CAP_STG;   // statistically never

        // zero the xh pad row (once)
        if (b == 0 && t < 16) ((unsigned int*)xh)[(size_t)ZROW * 16 + t] = 0;

        u.c.hist[t] = 0;
        __syncthreads();

        unsigned int rr[RPT];               // register staging: one global read
        #pragma unroll
        for (int j = 0; j < RPT; j++) {
            int i = t + j * 256;
            if (i < cnt) {
                rr[j] = buf[gbase + i];
                atomicAdd(&u.c.hist[rr[j] >> 18], 1);
            }
        }
        __syncthreads();

        int v  = u.c.hist[t];
        int pv = (v + 15) & ~15;            // padded row length
        u.c.scn[t] = pv;
        __syncthreads();
        for (int off = 1; off < 256; off <<= 1) {
            int x = (t >= off) ? u.c.scn[t - off] : 0;
            __syncthreads();
            u.c.scn[t] += x;
            __syncthreads();
        }
        int excl = u.c.scn[t] - pv;         // padded exclusive prefix
        int row = (b << 8) + t;
        if (row < TWO_N) {
            rs2[row] = make_int2(gbase + excl, v);
            __hip_atomic_store(&inv[row], rsqrtf((float)v + 1.0f),
                               __ATOMIC_RELAXED, __HIP_MEMORY_SCOPE_AGENT);
        }
        u.c.lcur[t] = excl;
        __syncthreads();

        // publish: inv for this bucket is complete
        if (t == 0)
            __hip_atomic_store(&flags[b], 1,
                               __ATOMIC_RELEASE, __HIP_MEMORY_SCOPE_AGENT);

        int tot = u.c.scn[255];
        if (tot > CAP_PAD) tot = CAP_PAD;   // statistically never

        for (int i = t; i < tot; i += 256) u.c.srt[i] = ZROW;   // pads pre-filled
        __syncthreads();

        #pragma unroll
        for (int j = 0; j < RPT; j++) {
            int i = t + j * 256;
            if (i < cnt) {
                int rk = atomicAdd(&u.c.lcur[rr[j] >> 18], 1);
                if (rk < CAP_PAD) u.c.srt[rk] = rr[j] & 0x3FFFFu;
            }
        }
        __syncthreads();

        // single coalesced streaming write of the whole padded bucket
        for (int i = t; i < tot; i += 256) buf[gbase + i] = u.c.srt[i];
    } else {
        // ------------------------------ ln role -------------------------------
        for (int i = t; i < H * H; i += 256) { u.l.sWp[i] = Wp[i]; u.l.sWn[i] = Wn[i]; }
        __syncthreads();

        int lane  = t & 31;
        int r     = t >> 5;
        int node0 = (blockIdx.x - NBUCK) * 8;
        int node  = node0 + r;              // < N_NODES by construction

        float x = h[node * H + lane];
        float s = x;
        #pragma unroll
        for (int m = 16; m >= 1; m >>= 1) s += __shfl_xor(s, m);
        float mu = s * (1.0f / 32.0f);
        float d  = x - mu;
        float vv = d * d;
        #pragma unroll
        for (int m = 16; m >= 1; m >>= 1) vv += __shfl_xor(vv, m);
        float rstd = rsqrtf(vv * (1.0f / 32.0f) + LN_EPS);
        float hn   = d * rstd * gamma[lane] + beta[lane];

        float accp = 0.f, accn = 0.f;
        #pragma unroll
        for (int k = 0; k < H; k++) {
            float hk = __shfl(hn, k, 32);
            accp += hk * u.l.sWp[k * H + lane];
            accn += hk * u.l.sWn[k * H + lane];
        }

        // acquire the bucket's inv (csr blocks were all dispatched before us)
        int b = node0 >> 7;                 // one bucket per ln block
        if (t == 0) {
            while (__hip_atomic_load(&flags[b], __ATOMIC_ACQUIRE,
                                     __HIP_MEMORY_SCOPE_AGENT) == 0)
                __builtin_amdgcn_s_sleep(8);
        }
        __syncthreads();

        float ivp = 0.f, ivn = 0.f;
        if (lane == 0) {
            ivp = __hip_atomic_load(&inv[2 * node],     __ATOMIC_RELAXED,
                                    __HIP_MEMORY_SCOPE_AGENT);
            ivn = __hip_atomic_load(&inv[2 * node + 1], __ATOMIC_RELAXED,
                                    __HIP_MEMORY_SCOPE_AGENT);
        }
        ivp = __shfl(ivp, 0, 32);
        ivn = __shfl(ivn, 0, 32);

        float vp = accp * ivp;
        float vn = accn * ivn;

        // pack feature pairs: even lane stores {self, odd-partner}
        float vp_nb = __shfl_xor(vp, 1);
        float vn_nb = __shfl_xor(vn, 1);
        if ((lane & 1) == 0) {
            __hip_bfloat162 pvv, nvv;
            pvv.x = __float2bfloat16(vp); pvv.y = __float2bfloat16(vp_nb);
            nvv.x = __float2bfloat16(vn); nvv.y = __float2bfloat16(vn_nb);
            int fp = lane >> 1;
            xh[(size_t)(2 * node) * 16 + fp]     = pvv;
            xh[(size_t)(2 * node + 1) * 16 + fp] = nvv;
        }
    }
}

// ---------------------------------------------------------------------------
// Kernel 3: atomic-free gather, wave per NODE (rows 2n/2n+1 interleaved),
// TAIL-FREE (lists padded to x16 with ZROW). 4 edges x 16 feature-pairs.
// Then bias + psi GEMV + tanh + damping. (R6-validated, 106.5 us)
// ---------------------------------------------------------------------------
__global__ __launch_bounds__(256) void gather_final_kernel(
    const float* __restrict__ h,
    const float* __restrict__ gamma,
    const float* __restrict__ beta,
    const __hip_bfloat162* __restrict__ xh,
    const int* __restrict__ slot,
    const float* __restrict__ inv,
    const int2* __restrict__ rs2,
    const float* __restrict__ bp,
    const float* __restrict__ bn,
    const float* __restrict__ Wpsi,
    float* __restrict__ out)
{
    __shared__ float sW[2 * H * H];
    __shared__ float sP[4][H];
    __shared__ float sM[4][H];

    int tid = threadIdx.x;
    for (int i = tid; i < 2 * H * H; i += 256) sW[i] = Wpsi[i];

    int wave = tid >> 6;
    int lane = tid & 63;
    int grp  = lane >> 4;        // edge group 0..3
    int fp   = lane & 15;        // feature pair 0..15
    int node = blockIdx.x * 4 + wave;
    int row  = 2 * node;         // pos row
    int rn   = 2 * node + 1;     // neg row

    int2 RP = rs2[row];          // {start, deg}
    int2 RN = rs2[rn];
    int np = (RP.y + 15) >> 4;   // full 16-edge chunks (padded)
    int nn = (RN.y + 15) >> 4;
    int nmax = np > nn ? np : nn;

    float ap0 = 0.f, ap1 = 0.f, an0 = 0.f, an1 = 0.f;
    int slp = 0, sln = 0;

    for (int c = 0; c < nmax; c++) {
        bool dop = c < np, don = c < nn;
        if ((c & 3) == 0) {
            if (dop) slp = slot[RP.x + (c << 4) + lane];
            if (don) sln = slot[RN.x + (c << 4) + lane];
        }
        int sb = ((c & 3) << 4) + (grp << 2);
        __hip_bfloat162 vp0, vp1, vp2, vp3, vn0, vn1, vn2, vn3;
        if (dop) {
            int s0 = __shfl(slp, sb + 0, 64), s1 = __shfl(slp, sb + 1, 64);
            int s2 = __shfl(slp, sb + 2, 64), s3 = __shfl(slp, sb + 3, 64);
            vp0 = xh[s0 * 16 + fp]; vp1 = xh[s1 * 16 + fp];
            vp2 = xh[s2 * 16 + fp]; vp3 = xh[s3 * 16 + fp];
        }
        if (don) {
            int s0 = __shfl(sln, sb + 0, 64), s1 = __shfl(sln, sb + 1, 64);
            int s2 = __shfl(sln, sb + 2, 64), s3 = __shfl(sln, sb + 3, 64);
            vn0 = xh[s0 * 16 + fp]; vn1 = xh[s1 * 16 + fp];
            vn2 = xh[s2 * 16 + fp]; vn3 = xh[s3 * 16 + fp];
        }
        if (dop) {
            ap0 += __bfloat162float(vp0.x) + __bfloat162float(vp1.x)
                 + __bfloat162float(vp2.x) + __bfloat162float(vp3.x);
            ap1 += __bfloat162float(vp0.y) + __bfloat162float(vp1.y)
                 + __bfloat162float(vp2.y) + __bfloat162float(vp3.y);
        }
        if (don) {
            an0 += __bfloat162float(vn0.x) + __bfloat162float(vn1.x)
                 + __bfloat162float(vn2.x) + __bfloat162float(vn3.x);
            an1 += __bfloat162float(vn0.y) + __bfloat162float(vn1.y)
                 + __bfloat162float(vn2.y) + __bfloat162float(vn3.y);
        }
    }

    // reduce across the 4 edge groups
    ap0 += __shfl_xor(ap0, 16); ap0 += __shfl_xor(ap0, 32);
    ap1 += __shfl_xor(ap1, 16); ap1 += __shfl_xor(ap1, 32);
    an0 += __shfl_xor(an0, 16); an0 += __shfl_xor(an0, 32);
    an1 += __shfl_xor(an1, 16); an1 += __shfl_xor(an1, 32);

    // self loops (already inv-scaled) + outer inv + bias
    __hip_bfloat162 svp = xh[row * 16 + fp];
    __hip_bfloat162 svn = xh[rn * 16 + fp];
    float ivp = inv[row], ivn = inv[rn];
    float hp0 = ivp * (ap0 + __bfloat162float(svp.x)) + bp[2 * fp];
    float hp1 = ivp * (ap1 + __bfloat162float(svp.y)) + bp[2 * fp + 1];
    float hm0 = ivn * (an0 + __bfloat162float(svn.x)) + bn[2 * fp];
    float hm1 = ivn * (an1 + __bfloat162float(svn.y)) + bn[2 * fp + 1];

    if (grp == 0) {
        sP[wave][2 * fp]     = hp0;
        sP[wave][2 * fp + 1] = hp1;
        sM[wave][2 * fp]     = hm0;
        sM[wave][2 * fp + 1] = hm1;
    }
    __syncthreads();

    // ---- epilogue: LN recompute + psi + tanh + damping + clip (128 thr) ----
    if (tid < 128) {
        int r     = tid >> 5;
        int lane2 = tid & 31;
        int node2 = blockIdx.x * 4 + r;

        float x = h[node2 * H + lane2];
        float s = x;
        #pragma unroll
        for (int m = 16; m >= 1; m >>= 1) s += __shfl_xor(s, m);
        float mu = s * (1.0f / 32.0f);
        float d  = x - mu;
        float v  = d * d;
        #pragma unroll
        for (int m = 16; m >= 1; m >>= 1) v += __shfl_xor(v, m);
        float rstd = rsqrtf(v * (1.0f / 32.0f) + LN_EPS);
        float hn   = d * rstd * gamma[lane2] + beta[lane2];

        float acc = 0.f;
        #pragma unroll
        for (int k = 0; k < H; k++) {
            acc += sP[r][k] * sW[k * H + lane2];
            acc += sM[r][k] * sW[(H + k) * H + lane2];
        }

        float delta = tanhf(acc) - DAMPING * hn;
        delta = fminf(fmaxf(delta, -50.f), 50.f);
        out[node2 * H + lane2] = delta;
    }
}

// ---------------------------------------------------------------------------
extern "C" void kernel_launch(void* const* d_in, const int* in_sizes, int n_in,
                              void* d_out, int out_size, void* d_ws, size_t ws_size,
                              hipStream_t stream)
{
    const float* h      = (const float*)d_in[1];
    const int*   ep     = (const int*)  d_in[2];   // (2, E)
    const int*   en     = (const int*)  d_in[3];
    const float* gamma  = (const float*)d_in[4];
    const float* beta   = (const float*)d_in[5];
    const float* Wp     = (const float*)d_in[6];
    const float* bp     = (const float*)d_in[7];
    const float* Wn     = (const float*)d_in[8];
    const float* bn     = (const float*)d_in[9];
    const float* Wpsi   = (const float*)d_in[10];
    float* out = (float*)d_out;

    // workspace layout (52.2 MB total):
    unsigned int* buf = (unsigned int*)d_ws;                     // NBUCK*CAP_PAD u32 (36.8 MB)
    __hip_bfloat162* xh = (__hip_bfloat162*)(buf + (size_t)NBUCK * CAP_PAD); // (2N+1)*16 (12.8 MB)
    int2*  rs2  = (int2*)(xh + (size_t)(TWO_N + 1) * 16);        // 2N int2 (1.6 MB)
    float* inv  = (float*)(rs2 + TWO_N);                         // 2N f32 (0.8 MB)
    int*   gcur = (int*)(inv + TWO_N);                           // NBUCK*16 (50 KB, line-padded)
    int*   flags = gcur + (size_t)NBUCK * GSTRIDE;               // NBUCK (3.1 KB)

    // one memset covers gcur + flags (contiguous)
    hipMemsetAsync(gcur, 0, (size_t)(NBUCK * GSTRIDE + NBUCK) * sizeof(int), stream);

    bucket_scatter_kernel<<<NBLK_A, 256, 0, stream>>>(ep, en, gcur, buf);

    mixed_csr_ln_kernel<<<NBUCK + NLN, 256, 0, stream>>>(
        gcur, buf, rs2, inv, flags, h, gamma, beta, Wp, Wn, xh);

    gather_final_kernel<<<N_NODES / 4, 256, 0, stream>>>(
        h, gamma, beta, xh, (const int*)buf, inv, rs2, bp, bn, Wpsi, out);
}

// Round 9
// 324.627 us; speedup vs baseline: 1.2605x; 1.2605x over previous
//
#include <hip/hip_runtime.h>
#include <hip/hip_bf16.h>
#include <math.h>

#define N_NODES 100000
#define NE      3200000
#define TWO_NE  (2 * NE)
#define TWO_N   (2 * N_NODES)
#define H       32
#define DAMPING 0.1f
#define LN_EPS  1e-5f

// Interleaved row ids: node r, sign s -> row' = 2r+s. Bucket = 256 rows = 128 nodes.
#define NBUCK    782           // ceil(2N / 256)
#define CAP_PAD  11776         // bucket region incl. 16-pads (mean padded 10112, +14 sigma)
#define CAP_STG  8960          // raw count cap (mean 8184 + 8.5 sigma)
#define RPT      ((CAP_STG + 255) / 256)   // 35 register-staged records per thread
#define EPB      8192          // edges per scatter block
#define NBLK_A   ((TWO_NE + EPB - 1) / EPB)   // 782
#define ZROW     TWO_N         // dedicated all-zero xh row used for padding
#define GSTRIDE  16            // gcur padding: one cursor per 64B line

// ---------------------------------------------------------------------------
// Kernel 1 (pass A): LDS counting-sort edges by coarse bucket (rank-first,
// one ds-atomic per edge), coalesced run writes of RAW records.
// Cursors are RELATIVE (memset-zeroed); absolute base = b*CAP_PAD.
// rec = (row' & 255) << 18 | src'   (interleaved ids < 2^18)
// [R6-validated, byte-for-byte]
// ---------------------------------------------------------------------------
__global__ __launch_bounds__(256) void bucket_scatter_kernel(
    const int* __restrict__ ep, const int* __restrict__ en,
    int* __restrict__ gcur, unsigned int* __restrict__ buf)
{
    __shared__ int lcur[NBUCK];            // rank counters -> final counts
    __shared__ int lexcl[NBUCK];
    __shared__ int claim[NBUCK];
    __shared__ int partial[256];
    __shared__ unsigned int srec[EPB];
    __shared__ unsigned short sbid[EPB];
    __shared__ unsigned short rnk[EPB];    // per-record rank within its bucket

    int t = threadIdx.x;
    for (int i = t; i < NBUCK; i += 256) lcur[i] = 0;
    __syncthreads();

    int base = blockIdx.x * EPB;
    unsigned int regR[EPB / 256];
    short regB[EPB / 256];
    #pragma unroll
    for (int j = 0; j < EPB / 1024; j++) {
        int i = base + (j * 256 + t) * 4;   // 4-aligned; never straddles NE
        if (i < TWO_NE) {
            int g = i >= NE;                // 0 = pos edge list, 1 = neg
            int e = i - g * NE;
            const int* eix = g ? en : ep;
            int4 s4 = *(const int4*)(eix + e);
            int4 d4 = *(const int4*)(eix + NE + e);
            int ss[4] = {s4.x, s4.y, s4.z, s4.w};
            int dd[4] = {d4.x, d4.y, d4.z, d4.w};
            #pragma unroll
            for (int k = 0; k < 4; k++) {
                int src = 2 * ss[k] + g;    // interleaved ids
                int dst = 2 * dd[k] + g;
                int b = dst >> 8;
                regB[j * 4 + k] = (short)b;
                regR[j * 4 + k] = ((unsigned int)(dst & 255) << 18) | (unsigned int)src;
                int r = atomicAdd(&lcur[b], 1);             // the ONLY per-edge atomic
                rnk[((j * 4 + k) << 8) + t] = (unsigned short)r;
            }
        } else {
            #pragma unroll
            for (int k = 0; k < 4; k++) regB[j * 4 + k] = -1;
        }
    }
    __syncthreads();

    // exclusive scan over lcur[0..NBUCK): 4 cells/thread + Hillis over partials
    int h0[4]; int ssum = 0;
    #pragma unroll
    for (int k = 0; k < 4; k++) {
        int idx = t * 4 + k;
        h0[k] = (idx < NBUCK) ? lcur[idx] : 0;
        ssum += h0[k];
    }
    partial[t] = ssum;
    __syncthreads();
    for (int off = 1; off < 256; off <<= 1) {
        int u = (t >= off) ? partial[t - off] : 0;
        __syncthreads();
        partial[t] += u;
        __syncthreads();
    }
    int run = partial[t] - ssum;
    #pragma unroll
    for (int k = 0; k < 4; k++) {
        int idx = t * 4 + k;
        if (idx < NBUCK) lexcl[idx] = run;
        run += h0[k];
    }
    __syncthreads();

    // claim contiguous global space per nonempty bucket (relative cursors)
    for (int b = t; b < NBUCK; b += 256) {
        int c = lcur[b];
        claim[b] = c ? (b * CAP_PAD + atomicAdd(&gcur[b * GSTRIDE], c)) : 0;
    }
    __syncthreads();

    // atomic-free placement: sorted position = lexcl[b] + stored rank
    #pragma unroll
    for (int j = 0; j < EPB / 256; j++) {
        int b = regB[j];
        if (b >= 0) {
            int s = lexcl[b] + rnk[(j << 8) + t];
            srec[s] = regR[j];
            sbid[s] = (unsigned short)b;
        }
    }
    __syncthreads();

    // coalesced-run writes: consecutive s within a bucket -> consecutive global
    int cnt = partial[255];
    for (int s = t; s < cnt; s += 256) {
        int b = sbid[s];
        buf[claim[b] + (s - lexcl[b])] = srec[s];
    }
}

// ---------------------------------------------------------------------------
// Kernel 2 (pass B, v2): SINGLE-ATOMIC-PASS counting sort per bucket.
// Pre-fill whole srt region with ZROW (no scan dependency, overlaps reads);
// one returning atomicAdd per record (rank in registers, final cnt = degree);
// wave-level __shfl_up scan (2 barriers, was 16); coalesced write-back.
// ---------------------------------------------------------------------------
__global__ __launch_bounds__(256) void csr_build_kernel(
    const int* __restrict__ gcur,
    unsigned int* __restrict__ buf,     // bucketed in, padded slots out (in-place)
    int2* __restrict__ rs2,
    float* __restrict__ inv,
    unsigned int* __restrict__ xhz)     // xh pad row (zeroed once by block 0)
{
    __shared__ unsigned int srt[CAP_PAD];   // 47.1 KB sorted+padded bucket
    __shared__ int cnt[256];                // rank counters -> degrees
    __shared__ int sexcl[256];
    __shared__ int wtot[4];
    __shared__ int tot_sh;

    int t = threadIdx.x;
    int b = blockIdx.x;
    int gbase = b * CAP_PAD;

    if (b == 0 && t < 16) xhz[t] = 0;       // zero the xh pad row (once)

    cnt[t] = 0;
    for (int i = t; i < CAP_PAD; i += 256) srt[i] = ZROW;   // pads pre-filled
    __syncthreads();

    int cv = gcur[b * GSTRIDE];             // relative count
    if (cv > CAP_STG) cv = CAP_STG;         // statistically never

    unsigned int rr[RPT];                   // register-staged records
    int rk[RPT];                            // register-staged ranks
    #pragma unroll
    for (int j = 0; j < RPT; j++) {
        int i = t + j * 256;
        if (i < cv) {
            rr[j] = buf[gbase + i];
            rk[j] = atomicAdd(&cnt[rr[j] >> 18], 1);   // the ONLY atomic pass
        }
    }
    __syncthreads();

    int v  = cnt[t];                        // degree of row t
    int pv = (v + 15) & ~15;                // padded row length

    // wave-level inclusive scan of pv over 256 cells (4 waves of 64)
    int lane = t & 63, w = t >> 6;
    int s = pv;
    #pragma unroll
    for (int m = 1; m < 64; m <<= 1) {
        int u = __shfl_up(s, m, 64);
        if (lane >= m) s += u;
    }
    if (lane == 63) wtot[w] = s;
    __syncthreads();
    int woff = 0;
    #pragma unroll
    for (int k = 0; k < 3; k++) woff += (k < w) ? wtot[k] : 0;
    int ex = woff + s - pv;                 // exclusive padded prefix

    int row = (b << 8) + t;
    if (row < TWO_N) {
        rs2[row] = make_int2(gbase + ex, v);
        inv[row] = rsqrtf((float)v + 1.0f);
    }
    sexcl[t] = ex;
    if (t == 255) tot_sh = ex + pv;
    __syncthreads();

    int tot = tot_sh;
    if (tot > CAP_PAD) tot = CAP_PAD;       // statistically never

    // place: position = excl[row] + register rank
    #pragma unroll
    for (int j = 0; j < RPT; j++) {
        int i = t + j * 256;
        if (i < cv) {
            int p = sexcl[rr[j] >> 18] + rk[j];
            if (p < CAP_PAD) srt[p] = rr[j] & 0x3FFFFu;
        }
    }
    __syncthreads();

    // single coalesced streaming write of the whole padded bucket
    for (int i = t; i < tot; i += 256) buf[gbase + i] = srt[i];
}

// ---------------------------------------------------------------------------
// Kernel 3: LayerNorm + two HxH GEMVs, outputs pre-scaled by inv[row'],
// packed to bf16 pairs in INTERLEAVED layout: row' = 2r (pos) / 2r+1 (neg).
// [R2/R4-validated]
// ---------------------------------------------------------------------------
__global__ __launch_bounds__(256) void ln_xw_kernel(
    const float* __restrict__ h,
    const float* __restrict__ gamma,
    const float* __restrict__ beta,
    const float* __restrict__ Wp,
    const float* __restrict__ Wn,
    const float* __restrict__ inv,
    __hip_bfloat162* __restrict__ xh)
{
    __shared__ float sWp[H * H];
    __shared__ float sWn[H * H];
    __shared__ float sHn[8][H];

    int tid = threadIdx.x;
    for (int i = tid; i < H * H; i += 256) { sWp[i] = Wp[i]; sWn[i] = Wn[i]; }

    int lane = tid & 31;
    int r    = tid >> 5;
    int row  = blockIdx.x * 8 + r;

    float x = h[row * H + lane];
    float s = x;
    #pragma unroll
    for (int m = 16; m >= 1; m >>= 1) s += __shfl_xor(s, m);
    float mu = s * (1.0f / 32.0f);
    float d  = x - mu;
    float v  = d * d;
    #pragma unroll
    for (int m = 16; m >= 1; m >>= 1) v += __shfl_xor(v, m);
    float rstd = rsqrtf(v * (1.0f / 32.0f) + LN_EPS);
    float hn   = d * rstd * gamma[lane] + beta[lane];

    sHn[r][lane] = hn;
    __syncthreads();

    float accp = 0.f, accn = 0.f;
    #pragma unroll
    for (int k = 0; k < H; k++) {
        float hk = sHn[r][k];
        accp += hk * sWp[k * H + lane];
        accn += hk * sWn[k * H + lane];
    }
    float vp = accp * inv[2 * row];
    float vn = accn * inv[2 * row + 1];

    // pack feature pairs: even lane stores {self, odd-partner}
    float vp_nb = __shfl_xor(vp, 1);
    float vn_nb = __shfl_xor(vn, 1);
    if ((lane & 1) == 0) {
        __hip_bfloat162 pv, nv;
        pv.x = __float2bfloat16(vp); pv.y = __float2bfloat16(vp_nb);
        nv.x = __float2bfloat16(vn); nv.y = __float2bfloat16(vn_nb);
        int fp = lane >> 1;
        xh[(2 * row) * 16 + fp]     = pv;
        xh[(2 * row + 1) * 16 + fp] = nv;
    }
}

// ---------------------------------------------------------------------------
// Kernel 4: atomic-free gather, wave per NODE (rows 2n/2n+1 interleaved),
// TAIL-FREE (lists padded to x16 with ZROW). 4 edges x 16 feature-pairs.
// Then bias + psi GEMV + tanh + damping. [R6-validated, 106.5 us]
// ---------------------------------------------------------------------------
__global__ __launch_bounds__(256) void gather_final_kernel(
    const float* __restrict__ h,
    const float* __restrict__ gamma,
    const float* __restrict__ beta,
    const __hip_bfloat162* __restrict__ xh,
    const int* __restrict__ slot,
    const float* __restrict__ inv,
    const int2* __restrict__ rs2,
    const float* __restrict__ bp,
    const float* __restrict__ bn,
    const float* __restrict__ Wpsi,
    float* __restrict__ out)
{
    __shared__ float sW[2 * H * H];
    __shared__ float sP[4][H];
    __shared__ float sM[4][H];

    int tid = threadIdx.x;
    for (int i = tid; i < 2 * H * H; i += 256) sW[i] = Wpsi[i];

    int wave = tid >> 6;
    int lane = tid & 63;
    int grp  = lane >> 4;        // edge group 0..3
    int fp   = lane & 15;        // feature pair 0..15
    int node = blockIdx.x * 4 + wave;
    int row  = 2 * node;         // pos row
    int rn   = 2 * node + 1;     // neg row

    int2 RP = rs2[row];          // {start, deg}
    int2 RN = rs2[rn];
    int np = (RP.y + 15) >> 4;   // full 16-edge chunks (padded)
    int nn = (RN.y + 15) >> 4;
    int nmax = np > nn ? np : nn;

    float ap0 = 0.f, ap1 = 0.f, an0 = 0.f, an1 = 0.f;
    int slp = 0, sln = 0;

    for (int c = 0; c < nmax; c++) {
        bool dop = c < np, don = c < nn;
        if ((c & 3) == 0) {
            if (dop) slp = slot[RP.x + (c << 4) + lane];
            if (don) sln = slot[RN.x + (c << 4) + lane];
        }
        int sb = ((c & 3) << 4) + (grp << 2);
        __hip_bfloat162 vp0, vp1, vp2, vp3, vn0, vn1, vn2, vn3;
        if (dop) {
            int s0 = __shfl(slp, sb + 0, 64), s1 = __shfl(slp, sb + 1, 64);
            int s2 = __shfl(slp, sb + 2, 64), s3 = __shfl(slp, sb + 3, 64);
            vp0 = xh[s0 * 16 + fp]; vp1 = xh[s1 * 16 + fp];
            vp2 = xh[s2 * 16 + fp]; vp3 = xh[s3 * 16 + fp];
        }
        if (don) {
            int s0 = __shfl(sln, sb + 0, 64), s1 = __shfl(sln, sb + 1, 64);
            int s2 = __shfl(sln, sb + 2, 64), s3 = __shfl(sln, sb + 3, 64);
            vn0 = xh[s0 * 16 + fp]; vn1 = xh[s1 * 16 + fp];
            vn2 = xh[s2 * 16 + fp]; vn3 = xh[s3 * 16 + fp];
        }
        if (dop) {
            ap0 += __bfloat162float(vp0.x) + __bfloat162float(vp1.x)
                 + __bfloat162float(vp2.x) + __bfloat162float(vp3.x);
            ap1 += __bfloat162float(vp0.y) + __bfloat162float(vp1.y)
                 + __bfloat162float(vp2.y) + __bfloat162float(vp3.y);
        }
        if (don) {
            an0 += __bfloat162float(vn0.x) + __bfloat162float(vn1.x)
                 + __bfloat162float(vn2.x) + __bfloat162float(vn3.x);
            an1 += __bfloat162float(vn0.y) + __bfloat162float(vn1.y)
                 + __bfloat162float(vn2.y) + __bfloat162float(vn3.y);
        }
    }

    // reduce across the 4 edge groups
    ap0 += __shfl_xor(ap0, 16); ap0 += __shfl_xor(ap0, 32);
    ap1 += __shfl_xor(ap1, 16); ap1 += __shfl_xor(ap1, 32);
    an0 += __shfl_xor(an0, 16); an0 += __shfl_xor(an0, 32);
    an1 += __shfl_xor(an1, 16); an1 += __shfl_xor(an1, 32);

    // self loops (already inv-scaled) + outer inv + bias
    __hip_bfloat162 svp = xh[row * 16 + fp];
    __hip_bfloat162 svn = xh[rn * 16 + fp];
    float ivp = inv[row], ivn = inv[rn];
    float hp0 = ivp * (ap0 + __bfloat162float(svp.x)) + bp[2 * fp];
    float hp1 = ivp * (ap1 + __bfloat162float(svp.y)) + bp[2 * fp + 1];
    float hm0 = ivn * (an0 + __bfloat162float(svn.x)) + bn[2 * fp];
    float hm1 = ivn * (an1 + __bfloat162float(svn.y)) + bn[2 * fp + 1];

    if (grp == 0) {
        sP[wave][2 * fp]     = hp0;
        sP[wave][2 * fp + 1] = hp1;
        sM[wave][2 * fp]     = hm0;
        sM[wave][2 * fp + 1] = hm1;
    }
    __syncthreads();

    // ---- epilogue: LN recompute + psi + tanh + damping + clip (128 thr) ----
    if (tid < 128) {
        int r     = tid >> 5;
        int lane2 = tid & 31;
        int node2 = blockIdx.x * 4 + r;

        float x = h[node2 * H + lane2];
        float s = x;
        #pragma unroll
        for (int m = 16; m >= 1; m >>= 1) s += __shfl_xor(s, m);
        float mu = s * (1.0f / 32.0f);
        float d  = x - mu;
        float v  = d * d;
        #pragma unroll
        for (int m = 16; m >= 1; m >>= 1) v += __shfl_xor(v, m);
        float rstd = rsqrtf(v * (1.0f / 32.0f) + LN_EPS);
        float hn   = d * rstd * gamma[lane2] + beta[lane2];

        float acc = 0.f;
        #pragma unroll
        for (int k = 0; k < H; k++) {
            acc += sP[r][k] * sW[k * H + lane2];
            acc += sM[r][k] * sW[(H + k) * H + lane2];
        }

        float delta = tanhf(acc) - DAMPING * hn;
        delta = fminf(fmaxf(delta, -50.f), 50.f);
        out[node2 * H + lane2] = delta;
    }
}

// ---------------------------------------------------------------------------
extern "C" void kernel_launch(void* const* d_in, const int* in_sizes, int n_in,
                              void* d_out, int out_size, void* d_ws, size_t ws_size,
                              hipStream_t stream)
{
    const float* h      = (const float*)d_in[1];
    const int*   ep     = (const int*)  d_in[2];   // (2, E)
    const int*   en     = (const int*)  d_in[3];
    const float* gamma  = (const float*)d_in[4];
    const float* beta   = (const float*)d_in[5];
    const float* Wp     = (const float*)d_in[6];
    const float* bp     = (const float*)d_in[7];
    const float* Wn     = (const float*)d_in[8];
    const float* bn     = (const float*)d_in[9];
    const float* Wpsi   = (const float*)d_in[10];
    float* out = (float*)d_out;

    // workspace layout (52.1 MB total):
    unsigned int* buf = (unsigned int*)d_ws;                     // NBUCK*CAP_PAD u32 (36.8 MB)
    __hip_bfloat162* xh = (__hip_bfloat162*)(buf + (size_t)NBUCK * CAP_PAD); // (2N+1)*16 (12.8 MB)
    int2*  rs2  = (int2*)(xh + (size_t)(TWO_N + 1) * 16);        // 2N int2 (1.6 MB)
    float* inv  = (float*)(rs2 + TWO_N);                         // 2N f32 (0.8 MB)
    int*   gcur = (int*)(inv + TWO_N);                           // NBUCK*16 (50 KB, line-padded)

    hipMemsetAsync(gcur, 0, (size_t)NBUCK * GSTRIDE * sizeof(int), stream);

    bucket_scatter_kernel<<<NBLK_A, 256, 0, stream>>>(ep, en, gcur, buf);

    csr_build_kernel<<<NBUCK, 256, 0, stream>>>(
        gcur, buf, rs2, inv, (unsigned int*)(xh + (size_t)ZROW * 16));

    ln_xw_kernel<<<N_NODES / 8, 256, 0, stream>>>(h, gamma, beta, Wp, Wn, inv, xh);

    gather_final_kernel<<<N_NODES / 4, 256, 0, stream>>>(
        h, gamma, beta, xh, (const int*)buf, inv, rs2, bp, bn, Wpsi, out);
}

// Round 10
// 310.100 us; speedup vs baseline: 1.3195x; 1.0468x over previous
//
#include <hip/hip_runtime.h>
#include <hip/hip_bf16.h>
#include <math.h>

#define N_NODES 100000
#define NE      3200000
#define TWO_NE  (2 * NE)
#define TWO_N   (2 * N_NODES)
#define H       32
#define DAMPING 0.1f
#define LN_EPS  1e-5f

#define NBUCK    782           // ceil(2N / 256) coarse dst buckets (256 rows each)
#define CAP_PAD  11776         // bucket region incl. 16-pads (mean padded 10112, +14 sigma)
#define CAP_STG  8960          // raw count cap (mean 8192 + 8.5 sigma)
#define RPT      ((CAP_STG + 255) / 256)   // 35 register-staged records per thread
#define EPB      8192          // edges per scatter block
#define NBLK_A   ((TWO_NE + EPB - 1) / EPB)   // 782
#define ZROW     TWO_N         // dedicated all-zero xh row used for padding
#define GSTRIDE  16            // gcur padding: one cursor per 64B line

// ---------------------------------------------------------------------------
// Kernel 0: init per-bucket cursors (line-padded) + zero the xh pad row.
// ---------------------------------------------------------------------------
__global__ __launch_bounds__(256) void init_kernel(
    int* __restrict__ gcur, unsigned int* __restrict__ xhz)
{
    int i = blockIdx.x * 256 + threadIdx.x;
    if (i < NBUCK) gcur[i * GSTRIDE] = i * CAP_PAD;
    if (i < 16)    xhz[i] = 0;             // xh row ZROW (16 x bf16x2 = 64 B)
}

// ---------------------------------------------------------------------------
// Kernel 1 (pass A): LDS counting-sort edges by coarse bucket.
// RANK-FIRST: ONE ds-atomic per edge (rank w/ return); counts come for free
// (lcur[b] after the pass), placement is atomic-free via stored u16 ranks.
// rec = (dst' & 255) << 18 | src'   (src' < 2^18)
// ---------------------------------------------------------------------------
__global__ __launch_bounds__(256) void bucket_scatter_kernel(
    const int* __restrict__ ep, const int* __restrict__ en,
    int* __restrict__ gcur, unsigned int* __restrict__ buf)
{
    __shared__ int lcur[NBUCK];            // rank counters -> final counts
    __shared__ int lexcl[NBUCK];
    __shared__ int claim[NBUCK];
    __shared__ int partial[256];
    __shared__ unsigned int srec[EPB];
    __shared__ unsigned short sbid[EPB];
    __shared__ unsigned short rnk[EPB];    // per-record rank within its bucket

    int t = threadIdx.x;
    for (int i = t; i < NBUCK; i += 256) lcur[i] = 0;
    __syncthreads();

    int base = blockIdx.x * EPB;
    unsigned int regR[EPB / 256];
    short regB[EPB / 256];
    #pragma unroll
    for (int j = 0; j < EPB / 1024; j++) {
        int i = base + (j * 256 + t) * 4;   // 4-aligned; never straddles NE
        if (i < TWO_NE) {
            int g = i >= NE;
            int e = i - g * NE;
            const int* eix = g ? en : ep;
            int4 s4 = *(const int4*)(eix + e);
            int4 d4 = *(const int4*)(eix + NE + e);
            int off = g * N_NODES;
            int ss[4] = {s4.x, s4.y, s4.z, s4.w};
            int dd[4] = {d4.x, d4.y, d4.z, d4.w};
            #pragma unroll
            for (int k = 0; k < 4; k++) {
                int src = ss[k] + off;
                int dst = dd[k] + off;
                int b = dst >> 8;
                regB[j * 4 + k] = (short)b;
                regR[j * 4 + k] = ((unsigned int)(dst & 255) << 18) | (unsigned int)src;
                int r = atomicAdd(&lcur[b], 1);             // the ONLY per-edge atomic
                rnk[((j * 4 + k) << 8) + t] = (unsigned short)r;  // coalesced u16 store
            }
        } else {
            #pragma unroll
            for (int k = 0; k < 4; k++) regB[j * 4 + k] = -1;
        }
    }
    __syncthreads();

    // exclusive scan over lcur[0..NBUCK): 4 cells/thread + Hillis over partials
    int h0[4]; int ssum = 0;
    #pragma unroll
    for (int k = 0; k < 4; k++) {
        int idx = t * 4 + k;
        h0[k] = (idx < NBUCK) ? lcur[idx] : 0;
        ssum += h0[k];
    }
    partial[t] = ssum;
    __syncthreads();
    for (int off = 1; off < 256; off <<= 1) {
        int u = (t >= off) ? partial[t - off] : 0;
        __syncthreads();
        partial[t] += u;
        __syncthreads();
    }
    int run = partial[t] - ssum;
    #pragma unroll
    for (int k = 0; k < 4; k++) {
        int idx = t * 4 + k;
        if (idx < NBUCK) lexcl[idx] = run;
        run += h0[k];
    }
    __syncthreads();

    // claim contiguous global space per nonempty bucket
    for (int b = t; b < NBUCK; b += 256) {
        int c = lcur[b];
        claim[b] = c ? atomicAdd(&gcur[b * GSTRIDE], c) : 0;
    }
    __syncthreads();

    // atomic-free placement: sorted position = lexcl[b] + stored rank
    #pragma unroll
    for (int j = 0; j < EPB / 256; j++) {
        int b = regB[j];
        if (b >= 0) {
            int s = lexcl[b] + rnk[(j << 8) + t];
            srec[s] = regR[j];
            sbid[s] = (unsigned short)b;
        }
    }
    __syncthreads();

    // coalesced-run writes: consecutive s within a bucket -> consecutive global
    int cnt = partial[255];
    for (int s = t; s < cnt; s += 256) {
        int b = sbid[s];
        buf[claim[b] + (s - lexcl[b])] = srec[s];
    }
}

// ---------------------------------------------------------------------------
// Kernel 2 (pass B): per bucket, register-staged counting sort into LDS,
// pads memset in LDS, ONE fully-coalesced streaming write-back.
// ---------------------------------------------------------------------------
__global__ __launch_bounds__(256) void csr_build_kernel(
    const int* __restrict__ gcur,
    unsigned int* __restrict__ buf,     // bucketed in, padded slots out (in-place)
    int2* __restrict__ rs2,
    float* __restrict__ inv)
{
    __shared__ unsigned int srt[CAP_PAD];   // 47.1 KB sorted+padded bucket
    __shared__ int hist[256];
    __shared__ int scn[256];
    __shared__ int lcur[256];

    int t = threadIdx.x;
    int b = blockIdx.x;
    int gbase = b * CAP_PAD;
    int cnt = gcur[b * GSTRIDE] - gbase;
    if (cnt > CAP_STG) cnt = CAP_STG;   // statistically never

    hist[t] = 0;
    __syncthreads();

    unsigned int rr[RPT];               // register staging: one global read total
    #pragma unroll
    for (int j = 0; j < RPT; j++) {
        int i = t + j * 256;
        if (i < cnt) {
            rr[j] = buf[gbase + i];
            atomicAdd(&hist[rr[j] >> 18], 1);
        }
    }
    __syncthreads();

    int v  = hist[t];
    int pv = (v + 15) & ~15;            // padded row length
    scn[t] = pv;
    __syncthreads();
    for (int off = 1; off < 256; off <<= 1) {
        int u = (t >= off) ? scn[t - off] : 0;
        __syncthreads();
        scn[t] += u;
        __syncthreads();
    }
    int excl = scn[t] - pv;             // padded exclusive prefix
    int row = (b << 8) + t;
    if (row < TWO_N) {
        rs2[row] = make_int2(gbase + excl, v);
        inv[row] = rsqrtf((float)v + 1.0f);
    }
    lcur[t] = excl;
    int tot = scn[255];
    if (tot > CAP_PAD) tot = CAP_PAD;   // statistically never
    __syncthreads();

    for (int i = t; i < tot; i += 256) srt[i] = ZROW;   // pads pre-filled
    __syncthreads();

    #pragma unroll
    for (int j = 0; j < RPT; j++) {
        int i = t + j * 256;
        if (i < cnt) {
            int rk = atomicAdd(&lcur[rr[j] >> 18], 1);
            if (rk < CAP_PAD) srt[rk] = rr[j] & 0x3FFFFu;
        }
    }
    __syncthreads();

    // single coalesced streaming write of the whole padded bucket
    for (int i = t; i < tot; i += 256) buf[gbase + i] = srt[i];
}

// ---------------------------------------------------------------------------
// Kernel 3: LayerNorm + two HxH GEMVs, outputs pre-scaled by inv[row],
// packed to bf16 pairs: xh[row][fp] = {feat 2fp, feat 2fp+1}, row' in [0,2N).
// ---------------------------------------------------------------------------
__global__ __launch_bounds__(256) void ln_xw_kernel(
    const float* __restrict__ h,
    const float* __restrict__ gamma,
    const float* __restrict__ beta,
    const float* __restrict__ Wp,
    const float* __restrict__ Wn,
    const float* __restrict__ inv,
    __hip_bfloat162* __restrict__ xh)
{
    __shared__ float sWp[H * H];
    __shared__ float sWn[H * H];
    __shared__ float sHn[8][H];

    int tid = threadIdx.x;
    for (int i = tid; i < H * H; i += 256) { sWp[i] = Wp[i]; sWn[i] = Wn[i]; }

    int lane = tid & 31;
    int r    = tid >> 5;
    int row  = blockIdx.x * 8 + r;

    float x = h[row * H + lane];
    float s = x;
    #pragma unroll
    for (int m = 16; m >= 1; m >>= 1) s += __shfl_xor(s, m);
    float mu = s * (1.0f / 32.0f);
    float d  = x - mu;
    float v  = d * d;
    #pragma unroll
    for (int m = 16; m >= 1; m >>= 1) v += __shfl_xor(v, m);
    float rstd = rsqrtf(v * (1.0f / 32.0f) + LN_EPS);
    float hn   = d * rstd * gamma[lane] + beta[lane];

    sHn[r][lane] = hn;
    __syncthreads();

    float accp = 0.f, accn = 0.f;
    #pragma unroll
    for (int k = 0; k < H; k++) {
        float hk = sHn[r][k];
        accp += hk * sWp[k * H + lane];
        accn += hk * sWn[k * H + lane];
    }
    float vp = accp * inv[row];
    float vn = accn * inv[N_NODES + row];

    // pack feature pairs: even lane stores {self, odd-partner}
    float vp_nb = __shfl_xor(vp, 1);
    float vn_nb = __shfl_xor(vn, 1);
    if ((lane & 1) == 0) {
        __hip_bfloat162 pv, nv;
        pv.x = __float2bfloat16(vp); pv.y = __float2bfloat16(vp_nb);
        nv.x = __float2bfloat16(vn); nv.y = __float2bfloat16(vn_nb);
        int fp = lane >> 1;
        xh[row * 16 + fp]               = pv;
        xh[(N_NODES + row) * 16 + fp]   = nv;
    }
}

// ---------------------------------------------------------------------------
// Kernel 4: atomic-free gather, wave per row, pos+neg interleaved, TAIL-FREE
// (lists padded to x16 with ZROW). 4 edges x 16 feature-pairs (best measured).
// Then bias + psi GEMV + tanh + damping.
// ---------------------------------------------------------------------------
__global__ __launch_bounds__(256) void gather_final_kernel(
    const float* __restrict__ h,
    const float* __restrict__ gamma,
    const float* __restrict__ beta,
    const __hip_bfloat162* __restrict__ xh,
    const int* __restrict__ slot,
    const float* __restrict__ inv,
    const int2* __restrict__ rs2,
    const float* __restrict__ bp,
    const float* __restrict__ bn,
    const float* __restrict__ Wpsi,
    float* __restrict__ out)
{
    __shared__ float sW[2 * H * H];
    __shared__ float sP[4][H];
    __shared__ float sM[4][H];

    int tid = threadIdx.x;
    for (int i = tid; i < 2 * H * H; i += 256) sW[i] = Wpsi[i];

    int wave = tid >> 6;
    int lane = tid & 63;
    int grp  = lane >> 4;        // edge group 0..3
    int fp   = lane & 15;        // feature pair 0..15
    int row  = blockIdx.x * 4 + wave;
    int rn   = N_NODES + row;

    int2 RP = rs2[row];          // {start, deg}
    int2 RN = rs2[rn];
    int np = (RP.y + 15) >> 4;   // full 16-edge chunks (padded)
    int nn = (RN.y + 15) >> 4;
    int nmax = np > nn ? np : nn;

    float ap0 = 0.f, ap1 = 0.f, an0 = 0.f, an1 = 0.f;
    int slp = 0, sln = 0;

    for (int c = 0; c < nmax; c++) {
        bool dop = c < np, don = c < nn;
        if ((c & 3) == 0) {
            if (dop) slp = slot[RP.x + (c << 4) + lane];
            if (don) sln = slot[RN.x + (c << 4) + lane];
        }
        int sb = ((c & 3) << 4) + (grp << 2);
        __hip_bfloat162 vp0, vp1, vp2, vp3, vn0, vn1, vn2, vn3;
        if (dop) {
            int s0 = __shfl(slp, sb + 0, 64), s1 = __shfl(slp, sb + 1, 64);
            int s2 = __shfl(slp, sb + 2, 64), s3 = __shfl(slp, sb + 3, 64);
            vp0 = xh[s0 * 16 + fp]; vp1 = xh[s1 * 16 + fp];
            vp2 = xh[s2 * 16 + fp]; vp3 = xh[s3 * 16 + fp];
        }
        if (don) {
            int s0 = __shfl(sln, sb + 0, 64), s1 = __shfl(sln, sb + 1, 64);
            int s2 = __shfl(sln, sb + 2, 64), s3 = __shfl(sln, sb + 3, 64);
            vn0 = xh[s0 * 16 + fp]; vn1 = xh[s1 * 16 + fp];
            vn2 = xh[s2 * 16 + fp]; vn3 = xh[s3 * 16 + fp];
        }
        if (dop) {
            ap0 += __bfloat162float(vp0.x) + __bfloat162float(vp1.x)
                 + __bfloat162float(vp2.x) + __bfloat162float(vp3.x);
            ap1 += __bfloat162float(vp0.y) + __bfloat162float(vp1.y)
                 + __bfloat162float(vp2.y) + __bfloat162float(vp3.y);
        }
        if (don) {
            an0 += __bfloat162float(vn0.x) + __bfloat162float(vn1.x)
                 + __bfloat162float(vn2.x) + __bfloat162float(vn3.x);
            an1 += __bfloat162float(vn0.y) + __bfloat162float(vn1.y)
                 + __bfloat162float(vn2.y) + __bfloat162float(vn3.y);
        }
    }

    // reduce across the 4 edge groups
    ap0 += __shfl_xor(ap0, 16); ap0 += __shfl_xor(ap0, 32);
    ap1 += __shfl_xor(ap1, 16); ap1 += __shfl_xor(ap1, 32);
    an0 += __shfl_xor(an0, 16); an0 += __shfl_xor(an0, 32);
    an1 += __shfl_xor(an1, 16); an1 += __shfl_xor(an1, 32);

    // self loops (already inv-scaled) + outer inv + bias
    __hip_bfloat162 svp = xh[row * 16 + fp];
    __hip_bfloat162 svn = xh[rn * 16 + fp];
    float ivp = inv[row], ivn = inv[rn];
    float hp0 = ivp * (ap0 + __bfloat162float(svp.x)) + bp[2 * fp];
    float hp1 = ivp * (ap1 + __bfloat162float(svp.y)) + bp[2 * fp + 1];
    float hm0 = ivn * (an0 + __bfloat162float(svn.x)) + bn[2 * fp];
    float hm1 = ivn * (an1 + __bfloat162float(svn.y)) + bn[2 * fp + 1];

    if (grp == 0) {
        sP[wave][2 * fp]     = hp0;
        sP[wave][2 * fp + 1] = hp1;
        sM[wave][2 * fp]     = hm0;
        sM[wave][2 * fp + 1] = hm1;
    }
    __syncthreads();

    // ---- epilogue: LN recompute + psi + tanh + damping + clip (128 thr) ----
    if (tid < 128) {
        int r     = tid >> 5;
        int lane2 = tid & 31;
        int row2  = blockIdx.x * 4 + r;

        float x = h[row2 * H + lane2];
        float s = x;
        #pragma unroll
        for (int m = 16; m >= 1; m >>= 1) s += __shfl_xor(s, m);
        float mu = s * (1.0f / 32.0f);
        float d  = x - mu;
        float v  = d * d;
        #pragma unroll
        for (int m = 16; m >= 1; m >>= 1) v += __shfl_xor(v, m);
        float rstd = rsqrtf(v * (1.0f / 32.0f) + LN_EPS);
        float hn   = d * rstd * gamma[lane2] + beta[lane2];

        float acc = 0.f;
        #pragma unroll
        for (int k = 0; k < H; k++) {
            acc += sP[r][k] * sW[k * H + lane2];
            acc += sM[r][k] * sW[(H + k) * H + lane2];
        }

        float delta = tanhf(acc) - DAMPING * hn;
        delta = fminf(fmaxf(delta, -50.f), 50.f);
        out[row2 * H + lane2] = delta;
    }
}

// ---------------------------------------------------------------------------
extern "C" void kernel_launch(void* const* d_in, const int* in_sizes, int n_in,
                              void* d_out, int out_size, void* d_ws, size_t ws_size,
                              hipStream_t stream)
{
    const float* h      = (const float*)d_in[1];
    const int*   ep     = (const int*)  d_in[2];   // (2, E)
    const int*   en     = (const int*)  d_in[3];
    const float* gamma  = (const float*)d_in[4];
    const float* beta   = (const float*)d_in[5];
    const float* Wp     = (const float*)d_in[6];
    const float* bp     = (const float*)d_in[7];
    const float* Wn     = (const float*)d_in[8];
    const float* bn     = (const float*)d_in[9];
    const float* Wpsi   = (const float*)d_in[10];
    float* out = (float*)d_out;

    // workspace layout (52.1 MB total):
    unsigned int* buf = (unsigned int*)d_ws;                     // NBUCK*CAP_PAD u32 (36.8 MB)
    __hip_bfloat162* xh = (__hip_bfloat162*)(buf + (size_t)NBUCK * CAP_PAD); // (2N+1)*16 (12.8 MB)
    int2*  rs2  = (int2*)(xh + (size_t)(TWO_N + 1) * 16);        // 2N int2 (1.6 MB)
    float* inv  = (float*)(rs2 + TWO_N);                         // 2N f32 (0.8 MB)
    int*   gcur = (int*)(inv + TWO_N);                           // NBUCK*16 (50 KB, line-padded)

    init_kernel<<<4, 256, 0, stream>>>(gcur, (unsigned int*)(xh + (size_t)ZROW * 16));

    bucket_scatter_kernel<<<NBLK_A, 256, 0, stream>>>(ep, en, gcur, buf);

    csr_build_kernel<<<NBUCK, 256, 0, stream>>>(gcur, buf, rs2, inv);

    ln_xw_kernel<<<N_NODES / 8, 256, 0, stream>>>(h, gamma, beta, Wp, Wn, inv, xh);

    gather_final_kernel<<<N_NODES / 4, 256, 0, stream>>>(
        h, gamma, beta, xh, (const int*)buf, inv, rs2, bp, bn, Wpsi, out);
}